// Round 1
// baseline (6646.031 us; speedup 1.0000x reference)
//
#include <hip/hip_runtime.h>
#include <math.h>

// LSTM: L=7 layers, H=49, B=1024, T=512, I=7, O=7. fp32 throughout.
//
// Design (round 1 baseline):
//  - One persistent-scan kernel launch per layer; batch partitioned across WGs
//    (S=2 samples/WG, grid=512 -> 2 WGs/CU). No cross-WG deps within a layer.
//  - Thread r (< 196) owns gate-row r: its 49(+49) weights live in VGPRs
//    (fully unrolled k loop). Activations (h, x_t) broadcast from LDS as float4.
//  - Gate pre-activations gathered through LDS 'pre'; threads j<49 do the
//    elementwise cell update and hold c[b] in registers across the whole scan.
//  - Input projection fused into the scan (no [T,B,4H] pre buffer).
//  - Inter-layer h buffer in d_ws ([B,T,49] fp32 = 102.8 MB), in-place for
//    layers 1..6 (x_t read before h_t write, barrier-separated, same WG).
//  - x_{t+1} prefetched into registers during compute to hide HBM latency.

constexpr int TT = 512;
constexpr int BB = 1024;
constexpr int HH = 49;
constexpr int GG = 196;   // 4*H

__device__ __forceinline__ float sigmoidf_(float x) {
    return 1.0f / (1.0f + __expf(-x));
}
__device__ __forceinline__ float tanhf_(float x) {
    // tanh(x) = 1 - 2/(exp(2x)+1); saturates correctly for large |x|.
    return 1.0f - 2.0f / (1.0f + __expf(2.0f * x));
}

template<int DIN>
__global__ __launch_bounds__(256, 2)
void lstm_layer_kernel(const float* xin,        // [B,T,DIN] (may alias hout!)
                       float* hout,             // [B,T,49]
                       const float* __restrict__ Wih,  // [196,DIN]
                       const float* __restrict__ Whh,  // [196,49]
                       const float* __restrict__ bih,  // [196]
                       const float* __restrict__ bhh)  // [196]
{
    constexpr int S   = 2;                 // samples per WG
    constexpr int DP4 = (DIN + 3) / 4;     // float4 chunks of input row
    constexpr int DP  = DP4 * 4;           // padded input width
    constexpr int HP4 = (HH + 3) / 4;      // 13
    constexpr int HP  = HP4 * 4;           // 52

    __shared__ float xact[S][DP];          // x_t staged (zero-padded tail)
    __shared__ float hact[S][HP];          // h_{t-1} staged (zero-padded tail)
    __shared__ float pre[S][GG];           // gate pre-activations

    const int tid = threadIdx.x;
    const int b0  = blockIdx.x * S;
    const int r   = tid;                   // gate row, active if r < 196

    // ---- weights pinned in VGPRs (padded with zeros so float4 tails are safe)
    float wih[DP];
    float whh[HP];
    float biasr = 0.0f;
    if (r < GG) {
        #pragma unroll
        for (int k = 0; k < DP; ++k)
            wih[k] = (k < DIN) ? Wih[r * DIN + k] : 0.0f;
        #pragma unroll
        for (int k = 0; k < HP; ++k)
            whh[k] = (k < HH) ? Whh[r * HH + k] : 0.0f;
        biasr = bih[r] + bhh[r];
    }

    // ---- zero LDS activation buffers (h0 = 0; also kills padding-tail NaNs)
    for (int i = tid; i < S * DP; i += 256) (&xact[0][0])[i] = 0.0f;
    for (int i = tid; i < S * HP; i += 256) (&hact[0][0])[i] = 0.0f;

    // ---- loader mapping (computed once)
    const int  lb = tid / DIN;
    const int  lk = tid - lb * DIN;
    const bool is_loader = (tid < S * DIN);
    const size_t xbase = is_loader ? ((size_t)(b0 + lb) * TT) * DIN + lk : 0;

    float c[S];
    #pragma unroll
    for (int b = 0; b < S; ++b) c[b] = 0.0f;

    // preload x_0
    if (is_loader) xact[lb][lk] = xin[xbase];
    __syncthreads();

    for (int t = 0; t < TT; ++t) {
        // prefetch x_{t+1} into a register; lands during compute phase
        float xnext = 0.0f;
        if (is_loader && (t + 1 < TT))
            xnext = xin[xbase + (size_t)(t + 1) * DIN];

        if (r < GG) {
            float acc[S];
            #pragma unroll
            for (int b = 0; b < S; ++b) acc[b] = biasr;

            #pragma unroll
            for (int k4 = 0; k4 < DP4; ++k4) {
                #pragma unroll
                for (int b = 0; b < S; ++b) {
                    const float4 xa = *(const float4*)&xact[b][k4 * 4];
                    acc[b] = fmaf(xa.x, wih[4 * k4 + 0], acc[b]);
                    acc[b] = fmaf(xa.y, wih[4 * k4 + 1], acc[b]);
                    acc[b] = fmaf(xa.z, wih[4 * k4 + 2], acc[b]);
                    acc[b] = fmaf(xa.w, wih[4 * k4 + 3], acc[b]);
                }
            }
            #pragma unroll
            for (int k4 = 0; k4 < HP4; ++k4) {
                #pragma unroll
                for (int b = 0; b < S; ++b) {
                    const float4 ha = *(const float4*)&hact[b][k4 * 4];
                    acc[b] = fmaf(ha.x, whh[4 * k4 + 0], acc[b]);
                    acc[b] = fmaf(ha.y, whh[4 * k4 + 1], acc[b]);
                    acc[b] = fmaf(ha.z, whh[4 * k4 + 2], acc[b]);
                    acc[b] = fmaf(ha.w, whh[4 * k4 + 3], acc[b]);
                }
            }
            #pragma unroll
            for (int b = 0; b < S; ++b) pre[b][r] = acc[b];
        }
        __syncthreads();   // pre ready; all reads of hact/xact done

        // elementwise cell update: thread j<49 owns cells (b, j), c in regs
        if (tid < HH) {
            #pragma unroll
            for (int b = 0; b < S; ++b) {
                const float gi = pre[b][tid];
                const float gf = pre[b][tid + HH];
                const float gg = pre[b][tid + 2 * HH];
                const float go = pre[b][tid + 3 * HH];
                const float i_ = sigmoidf_(gi);
                const float f_ = sigmoidf_(gf);
                const float g_ = tanhf_(gg);
                const float o_ = sigmoidf_(go);
                c[b] = f_ * c[b] + i_ * g_;
                const float h_ = o_ * tanhf_(c[b]);
                hact[b][tid] = h_;
                hout[((size_t)(b0 + b) * TT + t) * HH + tid] = h_;
            }
        }
        // safe to overwrite xact now (compute reads finished before barrier)
        if (is_loader) xact[lb][lk] = xnext;
        __syncthreads();   // hact/xact for t+1 visible to all
    }
}

__global__ __launch_bounds__(256)
void fc_kernel(const float* __restrict__ hbuf,  // [B,T,49]
               const float* __restrict__ fcw,   // [7,49]
               const float* __restrict__ fcb,   // [7]
               float* __restrict__ outp)        // [B,T,7]
{
    constexpr int HP = 52;
    __shared__ float w[7][HP];
    __shared__ float bsh[8];
    const int tid = threadIdx.x;
    for (int i = tid; i < 7 * HP; i += 256) {
        const int o = i / HP, k = i - o * HP;
        w[o][k] = (k < HH) ? fcw[o * HH + k] : 0.0f;
    }
    if (tid < 7) bsh[tid] = fcb[tid];
    __syncthreads();

    const size_t i = (size_t)blockIdx.x * 256 + tid;  // flat (b*T + t)
    float acc[7];
    #pragma unroll
    for (int j = 0; j < 7; ++j) acc[j] = bsh[j];
    const float* hp = hbuf + i * HH;
    #pragma unroll
    for (int k = 0; k < HH; ++k) {
        const float hv = hp[k];
        #pragma unroll
        for (int j = 0; j < 7; ++j) acc[j] = fmaf(hv, w[j][k], acc[j]);
    }
    #pragma unroll
    for (int j = 0; j < 7; ++j) outp[i * 7 + j] = acc[j];
}

extern "C" void kernel_launch(void* const* d_in, const int* in_sizes, int n_in,
                              void* d_out, int out_size, void* d_ws, size_t ws_size,
                              hipStream_t stream)
{
    const float* x    = (const float*)d_in[0];   // [B,T,7]
    const float* Wih0 = (const float*)d_in[1];   // [196,7]
    const float* Wihr = (const float*)d_in[2];   // [6,196,49]
    const float* Whh  = (const float*)d_in[3];   // [7,196,49]
    const float* bih  = (const float*)d_in[4];   // [7,196]
    const float* bhh  = (const float*)d_in[5];   // [7,196]
    const float* fcw  = (const float*)d_in[6];   // [7,49]
    const float* fcb  = (const float*)d_in[7];   // [7]
    float* outp = (float*)d_out;                 // [B,T,7]
    float* hbuf = (float*)d_ws;                  // [B,T,49] fp32 = 102.8 MB

    // layer 0: x -> hbuf
    lstm_layer_kernel<7><<<BB / 2, 256, 0, stream>>>(x, hbuf, Wih0, Whh, bih, bhh);
    // layers 1..6: hbuf -> hbuf (in-place)
    for (int l = 1; l < 7; ++l) {
        lstm_layer_kernel<49><<<BB / 2, 256, 0, stream>>>(
            hbuf, hbuf,
            Wihr + (size_t)(l - 1) * GG * HH,
            Whh  + (size_t)l * GG * HH,
            bih  + (size_t)l * GG,
            bhh  + (size_t)l * GG);
    }
    // final FC: hbuf -> out
    fc_kernel<<<(BB * TT) / 256, 256, 0, stream>>>(hbuf, fcw, fcb, outp);
}

// Round 2
// 5198.386 us; speedup vs baseline: 1.2785x; 1.2785x over previous
//
#include <hip/hip_runtime.h>
#include <math.h>

// LSTM: L=7 layers, H=49, B=1024, T=512, I=7, O=7. fp32.
//
// Round 2: LDS-broadcast-pipe relief.
//  Round-1 measurement: 4970 cy/step == 416 ds_read_b128 x ~12cy — the per-CU
//  LDS pipe (return-BW bound, broadcast NOT free) was the bottleneck, invariant
//  at ~3600/R cy where R = rows-per-thread. This kernel: R=4 rows/thread,
//  k split into 7 chunks of CHUNK floats mapped to 8-lane clusters; partial
//  sums reduced with DPP row_shl (VALU pipe, not LDS). Weights: 4xCHUNK <= 64
//  VGPRs per thread (round-1's 104 likely spilled; VGPR_Count was 68).
//  Chunk-offset rotation by kh keeps LDS accesses <=2-way bank aliased (free).

constexpr int TT = 512;
constexpr int BB = 1024;
constexpr int HH = 49;
constexpr int GG = 196;   // 4*H

__device__ __forceinline__ float sigmoidf_(float x) {
    return 1.0f / (1.0f + __expf(-x));
}
__device__ __forceinline__ float tanhf_(float x) {
    return 1.0f - 2.0f / (1.0f + __expf(2.0f * x));
}

// v += value of v from lane (lane + N) within the 16-lane DPP row.
// Out-of-row / exec-off sources read 0 (bound_ctrl). Cluster-of-8 sum lands on
// lanes with (lane&7)==0; their dependency cone stays inside the cluster.
template<int CTRL>
__device__ __forceinline__ float dpp_add(float v) {
    int s = __builtin_amdgcn_update_dpp(0, __float_as_int(v), CTRL, 0xF, 0xF, true);
    return v + __int_as_float(s);
}

template<int DIN, int CHUNK>
__global__ __launch_bounds__(448, 2)
void lstm_layer(const float* xin,               // [B,T,DIN] (may alias hout)
                float* hout,                    // [B,T,49]
                const float* __restrict__ Wih,  // [196,DIN]
                const float* __restrict__ Whh,  // [196,49]
                const float* __restrict__ bih,  // [196]
                const float* __restrict__ bhh)  // [196]
{
    constexpr int S    = 2;              // samples per WG
    constexpr int KTOT = DIN + HH;       // 56 (L0) or 98
    constexpr int KPAD = 7 * CHUNK;      // 56 or 112, >= KTOT
    constexpr int ASZ  = 8 * CHUNK;      // + one zero chunk for the pad lane
    constexpr int NC4  = CHUNK / 4;      // 2 or 4 float4s per chunk
    static_assert(KPAD >= KTOT, "chunking must cover k range");

    __shared__ float act[S][ASZ];        // [x_t | h_{t-1} | zeros]
    __shared__ float pre[S][GG];         // gate pre-activations (no bias)

    const int tid = threadIdx.x;
    const int b0  = blockIdx.x * S;
    const int g   = tid >> 3;            // row group: rows 4g..4g+3
    const int kh  = tid & 7;             // k-chunk; kh==7 is the pad lane
    const bool comp = (g < 49) && (kh < 7);

    // ---- per-chunk k offsets, rotated by kh so concurrent lanes stay <=2-way
    // bank aliased. Runtime values live in addresses only; all register-array
    // indices below are compile-time constants (SROA-safe).
    int koff[NC4];
    #pragma unroll
    for (int c = 0; c < NC4; ++c)
        koff[c] = kh * CHUNK + 4 * ((c + kh) & (NC4 - 1));

    // ---- weights in VGPRs, stored in rotated order to match koff
    float w[4][CHUNK];
    #pragma unroll
    for (int r = 0; r < 4; ++r) {
        #pragma unroll
        for (int c = 0; c < NC4; ++c) {
            #pragma unroll
            for (int i = 0; i < 4; ++i) {
                float wv = 0.0f;
                if (comp) {
                    const int k   = koff[c] + i;
                    const int row = 4 * g + r;
                    if (k < DIN)       wv = Wih[row * DIN + k];
                    else if (k < KTOT) wv = Whh[row * HH + (k - DIN)];
                }
                w[r][4 * c + i] = wv;
            }
        }
    }

    // ---- elementwise-update role: thread tid<98 owns cell (ew_s, ew_j)
    const int  ew_s  = tid / HH;
    const int  ew_j  = tid - ew_s * HH;
    const bool is_ew = (tid < S * HH);
    float cc = 0.0f;                                   // cell state, in reg
    float bi_ = 0.f, bf_ = 0.f, bg_ = 0.f, bo_ = 0.f;
    if (is_ew) {
        bi_ = bih[ew_j]          + bhh[ew_j];
        bf_ = bih[HH + ew_j]     + bhh[HH + ew_j];
        bg_ = bih[2 * HH + ew_j] + bhh[2 * HH + ew_j];
        bo_ = bih[3 * HH + ew_j] + bhh[3 * HH + ew_j];
    }

    // ---- x loader role
    const int  lb = tid / DIN;
    const int  lk = tid - lb * DIN;
    const bool is_loader = (tid < S * DIN);
    const size_t xbase = is_loader ? ((size_t)(b0 + lb) * TT) * DIN + lk : 0;

    // ---- zero act (h0 = 0, pad chunks stay finite forever)
    for (int i = tid; i < S * ASZ; i += 448) (&act[0][0])[i] = 0.0f;
    __syncthreads();
    if (is_loader) act[lb][lk] = xin[xbase];           // x_0
    __syncthreads();

    for (int t = 0; t < TT; ++t) {
        // prefetch x_{t+1}; value consumed before this iteration's 2nd barrier,
        // so in-place hout writes at t+1 (after that barrier) cannot race it.
        float xnext = 0.0f;
        if (is_loader && (t + 1 < TT))
            xnext = xin[xbase + (size_t)(t + 1) * DIN];

        float acc[4][S];
        #pragma unroll
        for (int r = 0; r < 4; ++r)
            #pragma unroll
            for (int s = 0; s < S; ++s) acc[r][s] = 0.0f;

        if (comp) {
            #pragma unroll
            for (int c = 0; c < NC4; ++c) {
                #pragma unroll
                for (int s = 0; s < S; ++s) {
                    const float4 a = *(const float4*)&act[s][koff[c]];
                    #pragma unroll
                    for (int r = 0; r < 4; ++r) {
                        acc[r][s] = fmaf(a.x, w[r][4 * c + 0], acc[r][s]);
                        acc[r][s] = fmaf(a.y, w[r][4 * c + 1], acc[r][s]);
                        acc[r][s] = fmaf(a.z, w[r][4 * c + 2], acc[r][s]);
                        acc[r][s] = fmaf(a.w, w[r][4 * c + 3], acc[r][s]);
                    }
                }
            }
        }

        // 8-lane cluster sum via DPP (all lanes active here; inactive-compute
        // lanes contribute their initialized 0). Result valid on kh==0 lanes.
        #pragma unroll
        for (int r = 0; r < 4; ++r) {
            #pragma unroll
            for (int s = 0; s < S; ++s) {
                float v = acc[r][s];
                v = dpp_add<0x104>(v);   // row_shl:4
                v = dpp_add<0x102>(v);   // row_shl:2
                v = dpp_add<0x101>(v);   // row_shl:1
                acc[r][s] = v;
            }
        }
        if (kh == 0 && g < 49) {
            #pragma unroll
            for (int s = 0; s < S; ++s) {
                float4 p;
                p.x = acc[0][s]; p.y = acc[1][s];
                p.z = acc[2][s]; p.w = acc[3][s];
                *(float4*)&pre[s][4 * g] = p;      // rows 4g..4g+3, 16B aligned
            }
        }
        __syncthreads();   // pre ready; act reads of this step done

        if (is_ew) {
            const float gi = pre[ew_s][ew_j]          + bi_;
            const float gf = pre[ew_s][ew_j + HH]     + bf_;
            const float gg = pre[ew_s][ew_j + 2 * HH] + bg_;
            const float go = pre[ew_s][ew_j + 3 * HH] + bo_;
            const float i_ = sigmoidf_(gi);
            const float f_ = sigmoidf_(gf);
            const float g_ = tanhf_(gg);
            const float o_ = sigmoidf_(go);
            cc = f_ * cc + i_ * g_;
            const float h_ = o_ * tanhf_(cc);
            act[ew_s][DIN + ew_j] = h_;
            hout[((size_t)(b0 + ew_s) * TT + t) * HH + ew_j] = h_;
        }
        if (is_loader) act[lb][lk] = xnext;
        __syncthreads();   // act(t+1) visible
    }
}

__global__ __launch_bounds__(256)
void fc_kernel(const float* __restrict__ hbuf,  // [B,T,49]
               const float* __restrict__ fcw,   // [7,49]
               const float* __restrict__ fcb,   // [7]
               float* __restrict__ outp)        // [B,T,7]
{
    constexpr int HP = 52;
    __shared__ float w[7][HP];
    __shared__ float bsh[8];
    const int tid = threadIdx.x;
    for (int i = tid; i < 7 * HP; i += 256) {
        const int o = i / HP, k = i - o * HP;
        w[o][k] = (k < HH) ? fcw[o * HH + k] : 0.0f;
    }
    if (tid < 7) bsh[tid] = fcb[tid];
    __syncthreads();

    const size_t i = (size_t)blockIdx.x * 256 + tid;   // flat (b*T + t)
    float acc[7];
    #pragma unroll
    for (int j = 0; j < 7; ++j) acc[j] = bsh[j];
    const float* hp = hbuf + i * HH;
    #pragma unroll
    for (int k = 0; k < HH; ++k) {
        const float hv = hp[k];
        #pragma unroll
        for (int j = 0; j < 7; ++j) acc[j] = fmaf(hv, w[j][k], acc[j]);
    }
    #pragma unroll
    for (int j = 0; j < 7; ++j) outp[i * 7 + j] = acc[j];
}

extern "C" void kernel_launch(void* const* d_in, const int* in_sizes, int n_in,
                              void* d_out, int out_size, void* d_ws, size_t ws_size,
                              hipStream_t stream)
{
    const float* x    = (const float*)d_in[0];   // [B,T,7]
    const float* Wih0 = (const float*)d_in[1];   // [196,7]
    const float* Wihr = (const float*)d_in[2];   // [6,196,49]
    const float* Whh  = (const float*)d_in[3];   // [7,196,49]
    const float* bih  = (const float*)d_in[4];   // [7,196]
    const float* bhh  = (const float*)d_in[5];   // [7,196]
    const float* fcw  = (const float*)d_in[6];   // [7,49]
    const float* fcb  = (const float*)d_in[7];   // [7]
    float* outp = (float*)d_out;                 // [B,T,7]
    float* hbuf = (float*)d_ws;                  // [B,T,49] fp32 = 102.8 MB

    // layer 0: x -> hbuf   (KTOT=56 = 7 chunks of 8, zero pad waste)
    lstm_layer<7, 8><<<BB / 2, 448, 0, stream>>>(x, hbuf, Wih0, Whh, bih, bhh);
    // layers 1..6: hbuf -> hbuf in-place  (KTOT=98 -> 7 chunks of 16)
    for (int l = 1; l < 7; ++l) {
        lstm_layer<49, 16><<<BB / 2, 448, 0, stream>>>(
            hbuf, hbuf,
            Wihr + (size_t)(l - 1) * GG * HH,
            Whh  + (size_t)l * GG * HH,
            bih  + (size_t)l * GG,
            bhh  + (size_t)l * GG);
    }
    fc_kernel<<<(BB * TT) / 256, 256, 0, stream>>>(hbuf, fcw, fcb, outp);
}

// Round 3
// 3499.481 us; speedup vs baseline: 1.8991x; 1.4855x over previous
//
#include <hip/hip_runtime.h>
#include <math.h>

// LSTM: L=7 layers, H=49, B=1024, T=512, I=7, O=7. fp32 in/out.
//
// Round 3: MFMA (bf16 hi/lo split) per-layer scan.
//  - Grid 256 WGs (1/CU), 448 threads (7 waves), S=4 samples/WG.
//  - Gate rows permuted r' = 4*j + gate  (j<49; j 49..51 zero-pad) so each
//    16-wide N-tile holds complete (i,f,g,o) quads -> EW reads are local.
//  - 13 N-tiles; wave w owns tiles {w, w+6} (wave 6: {12} + a zero dummy so
//    every wave issues the same 24 MFMAs -> SIMD-balanced).
//  - A ([x_t | h_{t-1}], K padded to 32*KSTEPS) stored in LDS in *fragment
//    order* (addr2B = (k>>5)*512 + ((k>>3)&3)*128 + m*8 + (k&7)) as separate
//    bf16 hi / lo planes; per k-step each lane does one conflict-free
//    ds_read_b128 per plane.
//  - fp32 fidelity via split: D += Ahi*Bhi + Alo*Bhi + Ahi*Blo (drop lo*lo).
//  - D (col=lane&15=n', row=quad*4+reg; valid rows = samples 0..3 on lanes
//    0..15) -> preT[n'][m] stride 5 (conflict-free) -> EW threads (j,m) do the
//    cell update, c in regs, write h back into A planes + hout global.
//  - 2 barriers/step. __syncthreads drains vmcnt -> x prefetch of h^{l-1}_{t+1}
//    (issued pre-b1) cannot race the in-place h^l write (post-b1).

constexpr int TT = 512;
constexpr int BB = 1024;
constexpr int HH = 49;
constexpr int GG = 196;

typedef __attribute__((ext_vector_type(8))) short short8;
typedef __attribute__((ext_vector_type(4))) float f32x4;

__device__ __forceinline__ float sigmoidf_(float x) {
    return 1.0f / (1.0f + __expf(-x));
}
__device__ __forceinline__ float tanhf_(float x) {
    return 1.0f - 2.0f / (1.0f + __expf(2.0f * x));
}

// round-to-nearest-even bf16 split: x ~= hi + lo (as fp32), |err| ~ 2^-17 |x|
__device__ __forceinline__ void bf16split(float x, short& hi, short& lo) {
    unsigned u = __float_as_uint(x);
    unsigned r = u + 0x7FFFu + ((u >> 16) & 1u);
    hi = (short)(r >> 16);
    float fhi = __uint_as_float(r & 0xFFFF0000u);
    float rem = x - fhi;
    unsigned u2 = __float_as_uint(rem);
    unsigned r2 = u2 + 0x7FFFu + ((u2 >> 16) & 1u);
    lo = (short)(r2 >> 16);
}

// fragment-order element address (in 2B units) of A[m][k]
__device__ __forceinline__ int addr2B(int m, int k) {
    return (k >> 5) * 512 + ((k >> 3) & 3) * 128 + m * 8 + (k & 7);
}

template<int DIN>
__global__ __launch_bounds__(448)
void lstm_mfma(const float* xin,                // [B,T,DIN] (may alias hout)
               float* hout,                     // [B,T,49]
               const float* __restrict__ Wih,   // [196,DIN]
               const float* __restrict__ Whh,   // [196,49]
               const float* __restrict__ bih,   // [196]
               const float* __restrict__ bhh)   // [196]
{
    constexpr int KTOT   = DIN + HH;            // 56 or 98
    constexpr int KSTEPS = (KTOT + 31) / 32;    // 2 or 4
    __shared__ short Ahi[KSTEPS * 512];         // bf16 hi plane, frag order
    __shared__ short Alo[KSTEPS * 512];         // bf16 lo plane
    __shared__ float preT[208 * 5];             // [n'][m], stride 5 (pad)

    const int tid  = threadIdx.x;
    const int wave = tid >> 6;
    const int lane = tid & 63;
    const int quad = lane >> 4;
    const int lrow = lane & 15;
    const int b0   = blockIdx.x * 4;

    // tile ownership: waves 0..5 -> {w, w+6}; wave 6 -> {12, dummy(zero)}
    const int ntiles = (wave < 6) ? 2 : 1;
    const int tile0  = (wave < 6) ? wave : 12;
    const int tile1  = wave + 6;                // only meaningful if ntiles==2

    // ---- B fragments (weights, static, hi/lo) in VGPRs -------------------
    short8 BH[2][KSTEPS], BL[2][KSTEPS];
    #pragma unroll
    for (int ti = 0; ti < 2; ++ti) {
        const int nt = (ti == 0) ? tile0 : tile1;
        #pragma unroll
        for (int ks = 0; ks < KSTEPS; ++ks) {
            #pragma unroll
            for (int jj = 0; jj < 8; ++jj) {
                const int k  = ks * 32 + quad * 8 + jj;
                const int np = nt * 16 + lrow;   // permuted row r' = 4j+g
                const int j  = np >> 2;
                const int g  = np & 3;
                float wv = 0.0f;
                if (ti < ntiles && j < HH && k < KTOT) {
                    const int r = g * HH + j;    // original W row (i,f,g,o)
                    wv = (k < DIN) ? Wih[r * DIN + k] : Whh[r * HH + (k - DIN)];
                }
                short h_, l_;
                bf16split(wv, h_, l_);
                BH[ti][ks][jj] = h_;
                BL[ti][ks][jj] = l_;
            }
        }
    }

    // ---- elementwise role: tid<196 owns (j = tid>>2, m = tid&3) ----------
    const bool is_ew = (tid < 4 * HH);
    const int  ew_m  = tid & 3;
    const int  ew_j  = tid >> 2;
    float bi_ = 0.f, bf_ = 0.f, bg_ = 0.f, bo_ = 0.f;
    int   haddr = 0;
    float* houtp = hout;
    if (is_ew) {
        bi_ = bih[ew_j]          + bhh[ew_j];
        bf_ = bih[HH + ew_j]     + bhh[HH + ew_j];
        bg_ = bih[2 * HH + ew_j] + bhh[2 * HH + ew_j];
        bo_ = bih[3 * HH + ew_j] + bhh[3 * HH + ew_j];
        haddr = addr2B(ew_m, DIN + ew_j);
        houtp = hout + ((size_t)(b0 + ew_m) * TT) * HH + ew_j;
    }
    float cc = 0.0f;

    // ---- loader role: tid in [196, 196+4*DIN) ----------------------------
    const int  lx        = tid - 4 * HH;
    const bool is_loader = (lx >= 0) && (lx < 4 * DIN);
    const int  ld_m = lx & 3;
    const int  ld_k = lx >> 2;
    const int  xaddr = is_loader ? addr2B(ld_m, ld_k) : 0;
    const size_t xbase = is_loader ? ((size_t)(b0 + ld_m) * TT) * DIN + ld_k : 0;

    // ---- zero A planes (pad k, pad m rows stay 0 forever) ----------------
    for (int i = tid; i < KSTEPS * 256; i += 448) {
        ((unsigned*)Ahi)[i] = 0u;
        ((unsigned*)Alo)[i] = 0u;
    }
    __syncthreads();
    if (is_loader) {                       // stage x_0
        short h_, l_;
        bf16split(xin[xbase], h_, l_);
        Ahi[xaddr] = h_;
        Alo[xaddr] = l_;
    }
    __syncthreads();

    for (int t = 0; t < TT; ++t) {
        // prefetch x_{t+1}; __syncthreads drains vmcnt, so this load completes
        // before any post-b1 in-place hout write can land.
        float xnext = 0.0f;
        if (is_loader && (t + 1 < TT))
            xnext = xin[xbase + (size_t)(t + 1) * DIN];

        // A fragments for this step (conflict-free b128, 2 planes)
        short8 AH[KSTEPS], AL[KSTEPS];
        #pragma unroll
        for (int ks = 0; ks < KSTEPS; ++ks) {
            AH[ks] = *(const short8*)&Ahi[ks * 512 + lane * 8];
            AL[ks] = *(const short8*)&Alo[ks * 512 + lane * 8];
        }

        #pragma unroll
        for (int ti = 0; ti < 2; ++ti) {
            f32x4 C = {0.f, 0.f, 0.f, 0.f};
            #pragma unroll
            for (int ks = 0; ks < KSTEPS; ++ks) {
                C = __builtin_amdgcn_mfma_f32_16x16x32_bf16(AH[ks], BH[ti][ks], C, 0, 0, 0);
                C = __builtin_amdgcn_mfma_f32_16x16x32_bf16(AL[ks], BH[ti][ks], C, 0, 0, 0);
                C = __builtin_amdgcn_mfma_f32_16x16x32_bf16(AH[ks], BL[ti][ks], C, 0, 0, 0);
            }
            // valid samples are rows 0..3 -> lanes 0..15, regs 0..3
            if (ti < ntiles && lane < 16) {
                const int nt = (ti == 0) ? tile0 : tile1;
                #pragma unroll
                for (int r = 0; r < 4; ++r)
                    preT[(nt * 16 + lane) * 5 + r] = C[r];
            }
        }
        __syncthreads();   // b1: preT ready; all A reads complete

        if (is_ew) {
            const float gi = preT[(4 * ew_j + 0) * 5 + ew_m] + bi_;
            const float gf = preT[(4 * ew_j + 1) * 5 + ew_m] + bf_;
            const float gg = preT[(4 * ew_j + 2) * 5 + ew_m] + bg_;
            const float go = preT[(4 * ew_j + 3) * 5 + ew_m] + bo_;
            const float i_ = sigmoidf_(gi);
            const float f_ = sigmoidf_(gf);
            const float g_ = tanhf_(gg);
            const float o_ = sigmoidf_(go);
            cc = f_ * cc + i_ * g_;
            const float hval = o_ * tanhf_(cc);
            short h_, l_;
            bf16split(hval, h_, l_);
            Ahi[haddr] = h_;
            Alo[haddr] = l_;
            houtp[(size_t)t * HH] = hval;
        }
        if (is_loader && (t + 1 < TT)) {
            short h_, l_;
            bf16split(xnext, h_, l_);
            Ahi[xaddr] = h_;
            Alo[xaddr] = l_;
        }
        __syncthreads();   // b2: A planes for t+1 visible
    }
}

__global__ __launch_bounds__(256)
void fc_kernel(const float* __restrict__ hbuf,  // [B,T,49]
               const float* __restrict__ fcw,   // [7,49]
               const float* __restrict__ fcb,   // [7]
               float* __restrict__ outp)        // [B,T,7]
{
    constexpr int HP = 52;
    __shared__ float w[7][HP];
    __shared__ float bsh[8];
    const int tid = threadIdx.x;
    for (int i = tid; i < 7 * HP; i += 256) {
        const int o = i / HP, k = i - o * HP;
        w[o][k] = (k < HH) ? fcw[o * HH + k] : 0.0f;
    }
    if (tid < 7) bsh[tid] = fcb[tid];
    __syncthreads();

    const size_t i = (size_t)blockIdx.x * 256 + tid;   // flat (b*T + t)
    float acc[7];
    #pragma unroll
    for (int j = 0; j < 7; ++j) acc[j] = bsh[j];
    const float* hp = hbuf + i * HH;
    #pragma unroll
    for (int k = 0; k < HH; ++k) {
        const float hv = hp[k];
        #pragma unroll
        for (int j = 0; j < 7; ++j) acc[j] = fmaf(hv, w[j][k], acc[j]);
    }
    #pragma unroll
    for (int j = 0; j < 7; ++j) outp[i * 7 + j] = acc[j];
}

extern "C" void kernel_launch(void* const* d_in, const int* in_sizes, int n_in,
                              void* d_out, int out_size, void* d_ws, size_t ws_size,
                              hipStream_t stream)
{
    const float* x    = (const float*)d_in[0];   // [B,T,7]
    const float* Wih0 = (const float*)d_in[1];   // [196,7]
    const float* Wihr = (const float*)d_in[2];   // [6,196,49]
    const float* Whh  = (const float*)d_in[3];   // [7,196,49]
    const float* bih  = (const float*)d_in[4];   // [7,196]
    const float* bhh  = (const float*)d_in[5];   // [7,196]
    const float* fcw  = (const float*)d_in[6];   // [7,49]
    const float* fcb  = (const float*)d_in[7];   // [7]
    float* outp = (float*)d_out;                 // [B,T,7]
    float* hbuf = (float*)d_ws;                  // [B,T,49] fp32 = 102.8 MB

    lstm_mfma<7><<<BB / 4, 448, 0, stream>>>(x, hbuf, Wih0, Whh, bih, bhh);
    for (int l = 1; l < 7; ++l) {
        lstm_mfma<49><<<BB / 4, 448, 0, stream>>>(
            hbuf, hbuf,
            Wihr + (size_t)(l - 1) * GG * HH,
            Whh  + (size_t)l * GG * HH,
            bih  + (size_t)l * GG,
            bhh  + (size_t)l * GG);
    }
    fc_kernel<<<(BB * TT) / 256, 256, 0, stream>>>(hbuf, fcw, fcb, outp);
}